// Round 9
// baseline (367.548 us; speedup 1.0000x reference)
//
#include <hip/hip_runtime.h>
#include <math.h>

#define BN 32
#define NP 1024
#define KNN 30
#define NR 64
#define NFPS 55

// xls slot with a 4-float skew every 128 rows: segment-parallel b128 reads
// land 2-way-conflicted at worst (free per m136); same-address reads across
// row-groups broadcast.
#define XSLOT(r) ((r) * 8 + ((r) >> 7) * 4)

// s = dinv*dinv with dinv = 1/sqrt(30) in f32, matching the reference's
// normalized laplacian (every kNN row-sum is exactly 30).
__device__ __forceinline__ float lap_s() {
    const float dv = 1.0f / sqrtf(30.0f);
    return dv * dv;
}

// Distance with ALL operations IEEE-pinned (contract off): guarantees the
// phase-A value and the phase-C recompute are bit-identical.
__device__ __forceinline__ float dist7(const float4& xiA, const float4& xiB,
                                       float sqi, const float4& ca, const float4& cb) {
#pragma clang fp contract(off)
    float dot = xiA.x * ca.x;
    dot = fmaf(xiA.y, ca.y, dot);
    dot = fmaf(xiA.z, ca.z, dot);
    dot = fmaf(xiA.w, ca.w, dot);
    dot = fmaf(xiB.x, cb.x, dot);
    dot = fmaf(xiB.y, cb.y, dot);
    dot = fmaf(xiB.z, cb.z, dot);
    float r = sqi + cb.w;
    r = r - 2.f * dot;
    return fmaxf(r, 0.f);
}

// ---------------------------------------------------------------------------
// k_knn: 16 rows/block (grid (B,64)), 4 waves, 16 lanes per row each
// scanning a 64-candidate segment (R9: was 8 lanes x 128 -- the med3
// insertion cost is per-candidate-per-lane, so 16 segments HALVES phase A
// and C VALU work; merge grows one shfl_xor level). In-wave 16-way bitonic
// merge (4 levels), T=m[29]; per-segment take/tie-quota/base from static
// compares + shuffles (tie -> lowest segment = ascending j, set semantics).
// Phase C: per-lane threshold rescan, ns via shfl butterfly, xs1 direct.
// ---------------------------------------------------------------------------
__global__ __launch_bounds__(256, 4) void k_knn(const float* __restrict__ x,
                                                int* __restrict__ knn,
                                                float* __restrict__ xs1) {
    __shared__ float xls[8224];            // 32896 B: 7 feats + sq, skewed
    int b = blockIdx.x;
    int t = threadIdx.x;
    int ln = t & 63, wv = t >> 6;
    int seg = ln & 15;                     // candidate segment 0..15
    int rl  = ln >> 4;                     // row-in-wave 0..3

    const float* xb = x + (size_t)b * NP * 7;
#pragma unroll 4
    for (int k = 0; k < 32; ++k) {
        int q = k * 256 + t;
        int r = q >> 3, d = q & 7;
        float v = (d < 7) ? xb[r * 7 + d] : 0.f;
        float p2 = v * v;
        p2 += __shfl_xor(p2, 1);
        p2 += __shfl_xor(p2, 2);
        p2 += __shfl_xor(p2, 4);
        xls[XSLOT(r) + d] = (d < 7) ? v : p2;
    }
    __syncthreads();

    int grow = blockIdx.y * 16 + wv * 4 + rl;
    int gslot = XSLOT(grow);
    float4 xiA = *(const float4*)&xls[gslot];
    float4 xiB = *(const float4*)&xls[gslot + 4];
    float sqi = xiB.w;

    // ---- phase A: per-lane branchless value top-30 over 64 candidates ----
    float bd[KNN];
#pragma unroll
    for (int q = 0; q < KNN; ++q) bd[q] = __builtin_inff();
    int jbase = seg * 64;
    int sbase = XSLOT(jbase);
    for (int jc = 0; jc < 64; jc += 4) {
        const float* p = &xls[sbase + jc * 8];
        float4 a0 = *(const float4*)(p +  0), b0 = *(const float4*)(p +  4);
        float4 a1 = *(const float4*)(p +  8), b1 = *(const float4*)(p + 12);
        float4 a2 = *(const float4*)(p + 16), b2 = *(const float4*)(p + 20);
        float4 a3 = *(const float4*)(p + 24), b3 = *(const float4*)(p + 28);
        float d0 = dist7(xiA, xiB, sqi, a0, b0);
        float d1 = dist7(xiA, xiB, sqi, a1, b1);
        float d2 = dist7(xiA, xiB, sqi, a2, b2);
        float d3 = dist7(xiA, xiB, sqi, a3, b3);
#pragma unroll
        for (int q = KNN - 1; q >= 1; --q) bd[q] = __builtin_amdgcn_fmed3f(bd[q - 1], d0, bd[q]);
        bd[0] = fminf(bd[0], d0);
#pragma unroll
        for (int q = KNN - 1; q >= 1; --q) bd[q] = __builtin_amdgcn_fmed3f(bd[q - 1], d1, bd[q]);
        bd[0] = fminf(bd[0], d1);
#pragma unroll
        for (int q = KNN - 1; q >= 1; --q) bd[q] = __builtin_amdgcn_fmed3f(bd[q - 1], d2, bd[q]);
        bd[0] = fminf(bd[0], d2);
#pragma unroll
        for (int q = KNN - 1; q >= 1; --q) bd[q] = __builtin_amdgcn_fmed3f(bd[q - 1], d3, bd[q]);
        bd[0] = fminf(bd[0], d3);
    }

    // ---- in-wave 16-way merge: 4 levels of bitonic halver + sort-32 ----
    float m[32];
#pragma unroll
    for (int q = 0; q < KNN; ++q) m[q] = bd[q];
    m[30] = __builtin_inff(); m[31] = __builtin_inff();
#pragma unroll
    for (int lvl = 0; lvl < 4; ++lvl) {
        int mask = 1 << lvl;
#pragma unroll
        for (int q = 0; q < 16; ++q) {
            float u = __shfl_xor(m[31 - q], mask);
            float v = __shfl_xor(m[q], mask);
            float lo = fminf(m[q], u);
            float hi = fminf(m[31 - q], v);
            m[q] = lo; m[31 - q] = hi;
        }
#pragma unroll
        for (int d = 16; d >= 1; d >>= 1) {
#pragma unroll
            for (int i = 0; i < 32; ++i) {
                if ((i & d) == 0) {
                    float a = m[i], c = m[i | d];
                    m[i] = fminf(a, c);
                    m[i | d] = fmaxf(a, c);
                }
            }
        }
    }
    float T = m[29];
    int firstT = 0;
#pragma unroll
    for (int q = 0; q < KNN; ++q) firstT += (m[q] < T) ? 1 : 0;
    int need = KNN - firstT;               // global tie quota at T
    int cnt_lt = 0, cnt_eq = 0;
#pragma unroll
    for (int q = 0; q < KNN; ++q) {
        cnt_lt += (bd[q] < T) ? 1 : 0;
        cnt_eq += (bd[q] == T) ? 1 : 0;
    }
    // per-segment tie quota (ascending segment = ascending j) and base
    int lanebase = ln & ~15;
    int pe = 0;
#pragma unroll
    for (int s2 = 0; s2 < 15; ++s2) {
        int v = __shfl(cnt_eq, lanebase + s2);
        pe += (s2 < seg) ? v : 0;
    }
    int e = need - pe;
    e = (e < 0) ? 0 : e;
    e = (e > cnt_eq) ? cnt_eq : e;
    int tk = cnt_lt + e;
    int pb = 0;
#pragma unroll
    for (int s2 = 0; s2 < 15; ++s2) {
        int v = __shfl(tk, lanebase + s2);
        pb += (s2 < seg) ? v : 0;
    }
    int base = pb;

    // ---- phase C: per-lane threshold rescan of own segment, emit + ns ----
    int* kout = knn + ((size_t)b * NP + grow) * KNN;
    float n0 = 0.f, n1 = 0.f, n2 = 0.f, n3 = 0.f, n4 = 0.f, n5 = 0.f, n6 = 0.f;
    int cs = 0, ct = 0;
    for (int jc = 0; jc < 64; jc += 4) {
        const float* p = &xls[sbase + jc * 8];
        float4 a0 = *(const float4*)(p +  0), b0 = *(const float4*)(p +  4);
        float4 a1 = *(const float4*)(p +  8), b1 = *(const float4*)(p + 12);
        float4 a2 = *(const float4*)(p + 16), b2 = *(const float4*)(p + 20);
        float4 a3 = *(const float4*)(p + 24), b3 = *(const float4*)(p + 28);
        float d0 = dist7(xiA, xiB, sqi, a0, b0);
        float d1 = dist7(xiA, xiB, sqi, a1, b1);
        float d2 = dist7(xiA, xiB, sqi, a2, b2);
        float d3 = dist7(xiA, xiB, sqi, a3, b3);
#pragma unroll
        for (int u = 0; u < 4; ++u) {
            float dist = (u == 0) ? d0 : (u == 1) ? d1 : (u == 2) ? d2 : d3;
            const float4& ca = (u == 0) ? a0 : (u == 1) ? a1 : (u == 2) ? a2 : a3;
            const float4& cb = (u == 0) ? b0 : (u == 1) ? b1 : (u == 2) ? b2 : b3;
            bool lt = dist < T;
            bool eq = (dist == T) && (ct < e);
            if ((lt || eq) && (cs + ct < tk)) {
                kout[base + cs + ct] = jbase + jc + u;
                cs += lt ? 1 : 0;
                ct += eq ? 1 : 0;
                n0 += ca.x; n1 += ca.y; n2 += ca.z; n3 += ca.w;
                n4 += cb.x; n5 += cb.y; n6 += cb.z;
            }
        }
    }
    for (int q = cs + ct; q < tk; ++q) kout[base + q] = grow;  // safety net
#pragma unroll
    for (int mask = 1; mask <= 8; mask <<= 1) {
        n0 += __shfl_xor(n0, mask);
        n1 += __shfl_xor(n1, mask);
        n2 += __shfl_xor(n2, mask);
        n3 += __shfl_xor(n3, mask);
        n4 += __shfl_xor(n4, mask);
        n5 += __shfl_xor(n5, mask);
        n6 += __shfl_xor(n6, mask);
    }
    if (seg < 7) {
        float nv = (seg == 0) ? n0 : (seg == 1) ? n1 : (seg == 2) ? n2 :
                   (seg == 3) ? n3 : (seg == 4) ? n4 : (seg == 5) ? n5 : n6;
        xs1[((size_t)b * NP + grow) * 7 + seg] = xls[gslot + seg] - lap_s() * nv;
    }
}

// ---------------------------------------------------------------------------
// k_out: xs2 = 2 L xs1 - x, then out = relu([x|xs1|xs2] @ W1 + b1), (B,N,64).
// Gather phase uses ALL 256 threads (4 per row, partials combined via LDS).
// y==16: zero Cbuf (all b); b==0 additionally does the one-off weight-reg init.
// ---------------------------------------------------------------------------
__global__ __launch_bounds__(256) void k_out(const float* __restrict__ x,
                                             const float* __restrict__ xs1,
                                             const int* __restrict__ knn,
                                             const float* __restrict__ W1,
                                             const float* __restrict__ b1,
                                             float* __restrict__ out,
                                             const float* __restrict__ fc1_w,
                                             const float* __restrict__ fc1_b,
                                             const float* __restrict__ fc3_w,
                                             const float* __restrict__ fc3_b,
                                             float* __restrict__ regs,
                                             float* __restrict__ Cbuf) {
    __shared__ float x1s[NP * 7];    // xs1 for ALL rows (neighbor gathers)
    __shared__ float x0s[64 * 7];    // x for this block's rows only
    __shared__ float fr[64 * 21];
    __shared__ float W1s[21 * 64];
    __shared__ float b1s[64];
    __shared__ float nsp[64 * 28];   // 4 partials x 7 dims per row
    int b = blockIdx.x, y = blockIdx.y;
    int t = threadIdx.x;
    if (y == 16) {                   // Cbuf zero (all b) + one-off init (b==0)
        float* cb = Cbuf + (size_t)b * 4096;
        for (int q = t; q < 4096; q += 256) cb[q] = 0.f;
        if (b != 0) return;
        float* r1 = x1s;             // overlay (x1s unused on this path)
        float* r2 = x1s + 256;
        float s1 = 0.f;
        for (int i = t; i < 512; i += 256) { float v = fc1_w[(size_t)i * 256]; s1 += v * v; }
        float v2 = fc3_w[(size_t)t * 40];
        r1[t] = s1; r2[t] = v2 * v2;
        __syncthreads();
        for (int st = 128; st > 0; st >>= 1) {
            if (t < st) { r1[t] += r1[t + st]; r2[t] += r2[t + st]; }
            __syncthreads();
        }
        if (t == 0) {
            regs[0] = 0.f; regs[1] = 0.f; regs[2] = 0.f;
            regs[3] = r1[0];
            regs[4] = fc1_b[0] * fc1_b[0];
            regs[5] = r2[0];
            regs[6] = fc3_b[0] * fc3_b[0];
        }
        return;
    }
    int rbase = y * 64;
    for (int q = t; q < NP * 7; q += 256) x1s[q] = xs1[(size_t)b * NP * 7 + q];
    for (int q = t; q < 64 * 7; q += 256) x0s[q] = x[(size_t)b * NP * 7 + (size_t)rbase * 7 + q];
    for (int q = t; q < 21 * 64; q += 256) W1s[q] = W1[q];
    if (t < 64) b1s[t] = b1[t];
    __syncthreads();
    {
        int row = t >> 2, tq = t & 3;
        int i = rbase + row;
        float ns[7] = {0.f, 0.f, 0.f, 0.f, 0.f, 0.f, 0.f};
        const int* kn = knn + ((size_t)b * NP + i) * KNN;
        for (int q = tq; q < KNN; q += 4) {
            int j = kn[q];
#pragma unroll
            for (int d = 0; d < 7; ++d) ns[d] += x1s[j * 7 + d];
        }
#pragma unroll
        for (int d = 0; d < 7; ++d) nsp[row * 28 + tq * 7 + d] = ns[d];
    }
    __syncthreads();
    if (t < 64) {
        int i = rbase + t;
        float f[21];
#pragma unroll
        for (int d = 0; d < 7; ++d) { f[d] = x0s[t * 7 + d]; f[7 + d] = x1s[i * 7 + d]; }
        const float s = lap_s();
#pragma unroll
        for (int d = 0; d < 7; ++d) {
            float ns = nsp[t * 28 + d] + nsp[t * 28 + 7 + d]
                     + nsp[t * 28 + 14 + d] + nsp[t * 28 + 21 + d];
            f[14 + d] = 2.f * (f[7 + d] - s * ns) - f[d];
        }
#pragma unroll
        for (int d = 0; d < 21; ++d) fr[t * 21 + d] = f[d];
    }
    __syncthreads();
    int o = t & 63, g = t >> 6;
    for (int m = 0; m < 16; ++m) {
        int r = g * 16 + m;
        float acc = b1s[o];
#pragma unroll
        for (int d = 0; d < 21; ++d) acc += fr[r * 21 + d] * W1s[d * 64 + o];
        out[((size_t)b * NP + rbase + r) * 64 + o] = fmaxf(acc, 0.f);
    }
}

// ---------------------------------------------------------------------------
// k_z1v: fused Z1 = L@out gather + segment-max pools. Grid (B, 256+16+55):
//   y<256  -> Z1 rows y*4..y*4+3
//   y<272  -> V_reeb rows (y-256)*4.. (16-segment max)
//   else   -> V_fps row p=y-272: 1024-bit dedupe bitmap
// ---------------------------------------------------------------------------
__global__ __launch_bounds__(256) void k_z1v(const float* __restrict__ out,
                                             const int* __restrict__ knn,
                                             const int* __restrict__ sccs,
                                             const int* __restrict__ sccs_fps,
                                             float* __restrict__ Z1,
                                             float* __restrict__ Vr,
                                             float* __restrict__ Vf) {
    __shared__ unsigned bmw[32];
    __shared__ float red[256];
    int b = blockIdx.x, y = blockIdx.y;
    int t = threadIdx.x;
    const float* ob = out + (size_t)b * NP * 64;
    if (y < 256) {
        int i = y * 4 + (t >> 6);
        int f = t & 63;
        const int* kn = knn + ((size_t)b * NP + i) * KNN;
        float sum = 0.f;
        for (int q = 0; q < KNN; ++q) sum += ob[(size_t)kn[q] * 64 + f];
        Z1[((size_t)b * NP + i) * 64 + f] = ob[(size_t)i * 64 + f] - lap_s() * sum;
    } else if (y < 272) {
        int r = (y - 256) * 4 + (t >> 6);
        int f = t & 63;
        const int* sc = sccs + ((size_t)b * NR + r) * 16;
        float m = -__builtin_inff();
        for (int q = 0; q < 16; ++q) m = fmaxf(m, ob[(size_t)sc[q] * 64 + f]);
        Vr[((size_t)b * NR + r) * 64 + f] = m;
    } else {
        int p = y - 272;
        const int* sp = sccs_fps + ((size_t)b * NFPS + p) * 1024;
        if (t < 32) bmw[t] = 0u;
        __syncthreads();
        for (int q = t; q < 1024; q += 256) {
            int r = sp[q];
            atomicOr(&bmw[r >> 5], 1u << (r & 31));
        }
        __syncthreads();
        int f = t & 63, sc = t >> 6;
        float m = -__builtin_inff();
        for (int w0 = sc * 8; w0 < sc * 8 + 8; ++w0) {
            unsigned w = bmw[w0];
            while (w) {
                int bit = __ffs(w) - 1;
                w &= w - 1;
                m = fmaxf(m, ob[(size_t)(w0 * 32 + bit) * 64 + f]);
            }
        }
        red[t] = m; __syncthreads();
        if (sc == 0) {
            m = fmaxf(fmaxf(red[f], red[64 + f]), fmaxf(red[128 + f], red[192 + f]));
            Vf[((size_t)b * NFPS + p) * 64 + f] = m;
        }
    }
}

// ---------------------------------------------------------------------------
// t1_part: partial C += out[chunk]^T @ Z1[chunk] (64x64, K-chunk of 128 rows),
// 4x4 register tile, atomicAdd into Cbuf[b].
// ---------------------------------------------------------------------------
__device__ __forceinline__ void t1_part(const float* __restrict__ out,
                                        const float* __restrict__ Z1,
                                        float* __restrict__ Cbuf,
                                        float* buf, int y) {
    int b = blockIdx.x, t = threadIdx.x;
    float* os = buf;          // 128*64
    float* zs = buf + 8192;   // 128*64
    const float* ob = out + ((size_t)b * NP + (size_t)y * 128) * 64;
    const float* zb = Z1 + ((size_t)b * NP + (size_t)y * 128) * 64;
    for (int q = t; q < 128 * 64; q += 256) { os[q] = ob[q]; zs[q] = zb[q]; }
    __syncthreads();
    int f0 = (t & 15) * 4, g0 = (t >> 4) * 4;
    float4 ac0 = make_float4(0.f, 0.f, 0.f, 0.f);
    float4 ac1 = ac0, ac2 = ac0, ac3 = ac0;
#pragma unroll 4
    for (int n = 0; n < 128; ++n) {
        float4 ov = *(const float4*)&os[n * 64 + f0];
        float4 zv = *(const float4*)&zs[n * 64 + g0];
        ac0.x += ov.x * zv.x; ac0.y += ov.x * zv.y; ac0.z += ov.x * zv.z; ac0.w += ov.x * zv.w;
        ac1.x += ov.y * zv.x; ac1.y += ov.y * zv.y; ac1.z += ov.y * zv.z; ac1.w += ov.y * zv.w;
        ac2.x += ov.z * zv.x; ac2.y += ov.z * zv.y; ac2.z += ov.z * zv.z; ac2.w += ov.z * zv.w;
        ac3.x += ov.w * zv.x; ac3.y += ov.w * zv.y; ac3.z += ov.w * zv.z; ac3.w += ov.w * zv.w;
    }
    float* cb = Cbuf + (size_t)b * 4096;
    atomicAdd(&cb[(f0 + 0) * 64 + g0 + 0], ac0.x);
    atomicAdd(&cb[(f0 + 0) * 64 + g0 + 1], ac0.y);
    atomicAdd(&cb[(f0 + 0) * 64 + g0 + 2], ac0.z);
    atomicAdd(&cb[(f0 + 0) * 64 + g0 + 3], ac0.w);
    atomicAdd(&cb[(f0 + 1) * 64 + g0 + 0], ac1.x);
    atomicAdd(&cb[(f0 + 1) * 64 + g0 + 1], ac1.y);
    atomicAdd(&cb[(f0 + 1) * 64 + g0 + 2], ac1.z);
    atomicAdd(&cb[(f0 + 1) * 64 + g0 + 3], ac1.w);
    atomicAdd(&cb[(f0 + 2) * 64 + g0 + 0], ac2.x);
    atomicAdd(&cb[(f0 + 2) * 64 + g0 + 1], ac2.y);
    atomicAdd(&cb[(f0 + 2) * 64 + g0 + 2], ac2.z);
    atomicAdd(&cb[(f0 + 2) * 64 + g0 + 3], ac2.w);
    atomicAdd(&cb[(f0 + 3) * 64 + g0 + 0], ac3.x);
    atomicAdd(&cb[(f0 + 3) * 64 + g0 + 1], ac3.y);
    atomicAdd(&cb[(f0 + 3) * 64 + g0 + 2], ac3.z);
    atomicAdd(&cb[(f0 + 3) * 64 + g0 + 3], ac3.w);
}

// ---------------------------------------------------------------------------
// lfps_impl: L_fps build from V_fps (R10-proven body)
// ---------------------------------------------------------------------------
__device__ __forceinline__ void lfps_impl(const float* __restrict__ Vfps,
                                          float* __restrict__ Lf, float* buf) {
    int b = blockIdx.x;
    int t = threadIdx.x;
    float* Vs = buf;                    // 55*64 = 3520
    float* sq = buf + 3520;             // 55 (pad to 3584)
    float* dist = buf + 3584;           // 55*55 = 3025
    float* dinv = buf + 6609;           // 55
    for (int q = t; q < NFPS * 64; q += 256) Vs[q] = Vfps[(size_t)b * NFPS * 64 + q];
    __syncthreads();
    if (t < NFPS) {
        float s = 0.f;
        for (int f = 0; f < 64; ++f) { float v = Vs[t * 64 + f]; s += v * v; }
        sq[t] = s;
    }
    __syncthreads();
    for (int q = t; q < NFPS * NFPS; q += 256) {
        int i = q / NFPS, j = q % NFPS;
        float dot = 0.f;
        for (int f = 0; f < 64; ++f) dot += Vs[i * 64 + f] * Vs[j * 64 + f];
        dist[q] = fmaxf(sq[i] + sq[j] - 2.f * dot, 0.f);
    }
    __syncthreads();
    if (t < NFPS) {
        float s = 0.f;
        for (int j = 0; j < NFPS; ++j) s += dist[t * NFPS + j];
        dinv[t] = (s > 0.f) ? 1.0f / sqrtf(fmaxf(s, 1e-12f)) : 0.f;
    }
    __syncthreads();
    for (int q = t; q < NFPS * NFPS; q += 256) {
        int i = q / NFPS, j = q % NFPS;
        Lf[(size_t)b * NFPS * NFPS + q] = ((i == j) ? 1.f : 0.f) - dist[q] * dinv[i] * dinv[j];
    }
}

// ---------------------------------------------------------------------------
// cheb_impl<N>: K=6 Chebyshev conv + relu + Z = L @ out, one batch, one
// 64-wide output-column slice. Register-tiled 4x4 per thread, float4 LDS
// reads both operands. Pad rows/cols zeroed so N=55 needs no read guards.
// m-loops pinned to unroll 2 (toolchain-drift defense; see R17/R5 notes:
// 112KB smem and 8-wide lane tiles are both proven regressions).
// ---------------------------------------------------------------------------
template<int N>
__device__ __forceinline__ void cheb_impl(const float* __restrict__ L,
                                          const float* __restrict__ V,
                                          const float* __restrict__ W,
                                          const float* __restrict__ bias,
                                          float* __restrict__ out,
                                          float* __restrict__ Z,
                                          float* Ls, float* bA, float* bB, float* Ws,
                                          int b, int sl) {
    constexpr int NPAD = (N + 3) & ~3;   // 64 or 56
    int t = threadIdx.x;
    int c0 = (t & 15) * 4;               // 0..60
    int r0 = (t >> 4) * 4;               // 0..60

    for (int q = t; q < 64 * 64; q += 256) { Ls[q] = 0.f; bA[q] = 0.f; bB[q] = 0.f; }
    __syncthreads();
    for (int q = t; q < N * N; q += 256) {
        int r = q / N, m = q % N;
        Ls[r * 64 + m] = L[(size_t)b * N * N + q];
    }
    for (int q = t; q < N * 64; q += 256) bA[q] = V[(size_t)b * N * 64 + q];
    {
        const float* Wk = W + sl * 64;
        for (int q = t; q < 64 * 64; q += 256) Ws[q] = Wk[(q >> 6) * 256 + (q & 63)];
    }
    float4 a4[4];
    {
        float4 bv = *(const float4*)&bias[sl * 64 + c0];
#pragma unroll
        for (int i = 0; i < 4; ++i) a4[i] = bv;
    }
    __syncthreads();

    auto accum = [&](const float* xb) {
#pragma unroll 2
        for (int m = 0; m < 64; m += 4) {
            float4 xv[4], wv[4];
#pragma unroll
            for (int i = 0; i < 4; ++i) xv[i] = *(const float4*)&xb[(r0 + i) * 64 + m];
#pragma unroll
            for (int mm = 0; mm < 4; ++mm) wv[mm] = *(const float4*)&Ws[(m + mm) * 64 + c0];
#pragma unroll
            for (int i = 0; i < 4; ++i) {
                float xi0 = xv[i].x, xi1 = xv[i].y, xi2 = xv[i].z, xi3 = xv[i].w;
                a4[i].x += xi0 * wv[0].x; a4[i].y += xi0 * wv[0].y; a4[i].z += xi0 * wv[0].z; a4[i].w += xi0 * wv[0].w;
                a4[i].x += xi1 * wv[1].x; a4[i].y += xi1 * wv[1].y; a4[i].z += xi1 * wv[1].z; a4[i].w += xi1 * wv[1].w;
                a4[i].x += xi2 * wv[2].x; a4[i].y += xi2 * wv[2].y; a4[i].z += xi2 * wv[2].z; a4[i].w += xi2 * wv[2].w;
                a4[i].x += xi3 * wv[3].x; a4[i].y += xi3 * wv[3].y; a4[i].z += xi3 * wv[3].z; a4[i].w += xi3 * wv[3].w;
            }
        }
    };
    auto chebmm = [&](const float* src, float* dst, bool first) {
        float4 acc[4];
#pragma unroll
        for (int i = 0; i < 4; ++i) acc[i] = make_float4(0.f, 0.f, 0.f, 0.f);
#pragma unroll 2
        for (int m = 0; m < NPAD; m += 4) {
            float4 sv[4], lv[4];
#pragma unroll
            for (int mm = 0; mm < 4; ++mm) sv[mm] = *(const float4*)&src[(m + mm) * 64 + c0];
#pragma unroll
            for (int i = 0; i < 4; ++i) lv[i] = *(const float4*)&Ls[(r0 + i) * 64 + m];
#pragma unroll
            for (int i = 0; i < 4; ++i) {
                float l0 = lv[i].x, l1 = lv[i].y, l2 = lv[i].z, l3 = lv[i].w;
                acc[i].x += l0 * sv[0].x; acc[i].y += l0 * sv[0].y; acc[i].z += l0 * sv[0].z; acc[i].w += l0 * sv[0].w;
                acc[i].x += l1 * sv[1].x; acc[i].y += l1 * sv[1].y; acc[i].z += l1 * sv[1].z; acc[i].w += l1 * sv[1].w;
                acc[i].x += l2 * sv[2].x; acc[i].y += l2 * sv[2].y; acc[i].z += l2 * sv[2].z; acc[i].w += l2 * sv[2].w;
                acc[i].x += l3 * sv[3].x; acc[i].y += l3 * sv[3].y; acc[i].z += l3 * sv[3].z; acc[i].w += l3 * sv[3].w;
            }
        }
#pragma unroll
        for (int i = 0; i < 4; ++i) {
            if (r0 + i < N) {
                float4* d = (float4*)&dst[(r0 + i) * 64 + c0];
                if (first) *d = acc[i];
                else {
                    float4 od = *d;
                    *d = make_float4(2.f * acc[i].x - od.x, 2.f * acc[i].y - od.y,
                                     2.f * acc[i].z - od.z, 2.f * acc[i].w - od.w);
                }
            }
        }
    };
    auto loadW = [&](int k) {
        const float* Wk = W + (size_t)k * 64 * 256 + sl * 64;
        for (int q = t; q < 64 * 64; q += 256) Ws[q] = Wk[(q >> 6) * 256 + (q & 63)];
    };

    accum(bA);                 __syncthreads();
    chebmm(bA, bB, true);      loadW(1);  __syncthreads();
    accum(bB);                 __syncthreads();
    chebmm(bB, bA, false);     loadW(2);  __syncthreads();
    accum(bA);                 __syncthreads();
    chebmm(bA, bB, false);     loadW(3);  __syncthreads();
    accum(bB);                 __syncthreads();
    chebmm(bB, bA, false);     loadW(4);  __syncthreads();
    accum(bA);                 __syncthreads();
    chebmm(bA, bB, false);     loadW(5);  __syncthreads();
    accum(bB);                 __syncthreads();

    float* ob = out + (size_t)b * N * 256 + sl * 64;
#pragma unroll
    for (int i = 0; i < 4; ++i) {
        if (r0 + i < N) {
            float4 v = make_float4(fmaxf(a4[i].x, 0.f), fmaxf(a4[i].y, 0.f),
                                   fmaxf(a4[i].z, 0.f), fmaxf(a4[i].w, 0.f));
            *(float4*)&bA[(r0 + i) * 64 + c0] = v;
            *(float4*)&ob[(size_t)(r0 + i) * 256 + c0] = v;
        }
    }
    __syncthreads();
    {
        float4 acc[4];
#pragma unroll
        for (int i = 0; i < 4; ++i) acc[i] = make_float4(0.f, 0.f, 0.f, 0.f);
#pragma unroll 2
        for (int m = 0; m < NPAD; m += 4) {
            float4 sv[4], lv[4];
#pragma unroll
            for (int mm = 0; mm < 4; ++mm) sv[mm] = *(const float4*)&bA[(m + mm) * 64 + c0];
#pragma unroll
            for (int i = 0; i < 4; ++i) lv[i] = *(const float4*)&Ls[(r0 + i) * 64 + m];
#pragma unroll
            for (int i = 0; i < 4; ++i) {
                float l0 = lv[i].x, l1 = lv[i].y, l2 = lv[i].z, l3 = lv[i].w;
                acc[i].x += l0 * sv[0].x; acc[i].y += l0 * sv[0].y; acc[i].z += l0 * sv[0].z; acc[i].w += l0 * sv[0].w;
                acc[i].x += l1 * sv[1].x; acc[i].y += l1 * sv[1].y; acc[i].z += l1 * sv[1].z; acc[i].w += l1 * sv[1].w;
                acc[i].x += l2 * sv[2].x; acc[i].y += l2 * sv[2].y; acc[i].z += l2 * sv[2].z; acc[i].w += l2 * sv[2].w;
                acc[i].x += l3 * sv[3].x; acc[i].y += l3 * sv[3].y; acc[i].z += l3 * sv[3].z; acc[i].w += l3 * sv[3].w;
            }
        }
        float* zb = Z + (size_t)b * N * 256 + sl * 64;
#pragma unroll
        for (int i = 0; i < 4; ++i)
            if (r0 + i < N) *(float4*)&zb[(size_t)(r0 + i) * 256 + c0] = acc[i];
    }
}

// ---------------------------------------------------------------------------
// treg_impl<N>: reg += sum((out^T Z)^2) for one (f-tile, g-half) pair.
// (R7 lesson: the 2x-cheaper Gram form LOST 10us -- 32 blocks/network vs
// 512+: at this scale block count beats op count. Keep treg.)
// ---------------------------------------------------------------------------
template<int N>
__device__ __forceinline__ void treg_impl(const float* __restrict__ out,
                                          const float* __restrict__ Z,
                                          float* __restrict__ reg,
                                          float* zs, float* os, float* red, int y) {
    int b = blockIdx.x;
    int f0 = (y >> 1) * 32;
    int g0 = (y & 1) * 128;
    int t = threadIdx.x;
    for (int q = t; q < N * 128; q += 256) {
        int r = q >> 7, gl = q & 127;
        zs[q] = Z[(size_t)b * N * 256 + r * 256 + g0 + gl];
    }
    for (int q = t; q < N * 32; q += 256) {
        int r = q >> 5, f = q & 31;
        os[q] = out[(size_t)b * N * 256 + r * 256 + f0 + f];
    }
    __syncthreads();
    int fl = t >> 3;           // 0..31
    int gb = (t & 7) * 16;     // 0..112
    float accv[16];
#pragma unroll
    for (int q = 0; q < 16; ++q) accv[q] = 0.f;
    for (int n = 0; n < N; ++n) {
        float a = os[n * 32 + fl];
        const float* zr = zs + n * 128 + gb;
#pragma unroll
        for (int q = 0; q < 16; ++q) accv[q] += a * zr[q];
    }
    float loc = 0.f;
#pragma unroll
    for (int q = 0; q < 16; ++q) loc += accv[q] * accv[q];
    red[t] = loc; __syncthreads();
    for (int st = 128; st > 0; st >>= 1) { if (t < st) red[t] += red[t + st]; __syncthreads(); }
    if (t == 0) atomicAdd(reg, red[0]);
}

// ---------------------------------------------------------------------------
// k_mid1: fused independent stage (R6-proven arrangement). Grid (B, 13):
//   y<8  -> t1 partial C chunk y (rows y*128..)
//   y==8 -> L_fps build (read by k_mid2 next launch)
//   y>8  -> cheb_reeb output slice y-9
// ---------------------------------------------------------------------------
__global__ __launch_bounds__(256) void k_mid1(
        const float* __restrict__ out, const float* __restrict__ Z1,
        const float* __restrict__ Vfps, float* __restrict__ Cbuf,
        float* __restrict__ Lf,
        const float* __restrict__ Lr, const float* __restrict__ Vr,
        const float* __restrict__ Wr, const float* __restrict__ br,
        float* __restrict__ outR, float* __restrict__ Zr) {
    __shared__ float smem[16384];    // 64 KB union
    int y = blockIdx.y;
    if (y < 8)       t1_part(out, Z1, Cbuf, smem, y);
    else if (y == 8) lfps_impl(Vfps, Lf, smem);
    else cheb_impl<NR>(Lr, Vr, Wr, br, outR, Zr,
                       smem, smem + 4096, smem + 8192, smem + 12288,
                       blockIdx.x, y - 9);
}

// ---------------------------------------------------------------------------
// k_mid2: Grid (B, 21): y<4 -> cheb_fps slice y (needs L_fps from k_mid1);
//   y in 4..19 -> treg_reeb tile y-4 (needs outR/Zr from k_mid1);
//   y==20 -> reg1 = sum(Cbuf^2) (needs all t1 partials from k_mid1).
// ---------------------------------------------------------------------------
__global__ __launch_bounds__(256) void k_mid2(
        const float* __restrict__ Lf, const float* __restrict__ Vf,
        const float* __restrict__ Wf, const float* __restrict__ bf,
        float* __restrict__ outP, float* __restrict__ Zf,
        const float* __restrict__ outR, const float* __restrict__ Zr,
        const float* __restrict__ Cbuf, float* __restrict__ regs) {
    __shared__ float smem[16384];    // 64 KB union
    int y = blockIdx.y;
    if (y < 4) cheb_impl<NFPS>(Lf, Vf, Wf, bf, outP, Zf,
                               smem, smem + 4096, smem + 8192, smem + 12288,
                               blockIdx.x, y);
    else if (y < 20) treg_impl<NR>(outR, Zr, regs + 1, smem, smem + 8192, smem + 10240, y - 4);
    else {
        int b = blockIdx.x, t = threadIdx.x;
        float* red = smem;
        float loc = 0.f;
        for (int q = t; q < 4096; q += 256) { float v = Cbuf[(size_t)b * 4096 + q]; loc += v * v; }
        red[t] = loc; __syncthreads();
        for (int st = 128; st > 0; st >>= 1) { if (t < st) red[t] += red[t + st]; __syncthreads(); }
        if (t == 0) atomicAdd(&regs[0], red[0]);
    }
}

// ---------------------------------------------------------------------------
// k_fin: Grid (B, 17): y<16 -> treg_fps tile y (needs outP/Zf from k_mid2);
//   y==16 -> per-batch maxpool + MLP -> logits.
// ---------------------------------------------------------------------------
__global__ __launch_bounds__(256) void k_fin(
        const float* __restrict__ outP, const float* __restrict__ Zf,
        const float* __restrict__ outR,
        const float* __restrict__ fc1_w, const float* __restrict__ fc1_b,
        const float* __restrict__ fc3_w, const float* __restrict__ fc3_b,
        float* __restrict__ regs, float* __restrict__ logits) {
    __shared__ float smem[10496];    // 41 KB
    int y = blockIdx.y;
    if (y < 16) treg_impl<NFPS>(outP, Zf, regs + 2, smem, smem + 8192, smem + 10240, y);
    else {
        int b = blockIdx.x, t = threadIdx.x;
        float* feat = smem;            // 512 floats
        float* h = smem + 1024;        // 256 floats
        float m = -__builtin_inff();
        for (int r = 0; r < NR; ++r) m = fmaxf(m, outR[((size_t)b * NR + r) * 256 + t]);
        feat[t] = m;
        m = -__builtin_inff();
        for (int p = 0; p < NFPS; ++p) m = fmaxf(m, outP[((size_t)b * NFPS + p) * 256 + t]);
        feat[256 + t] = m;
        __syncthreads();
        float a = fc1_b[t];
        for (int i = 0; i < 512; ++i) a += feat[i] * fc1_w[(size_t)i * 256 + t];
        h[t] = fmaxf(a, 0.f);
        __syncthreads();
        if (t < 40) {
            float a2 = fc3_b[t];
            for (int i = 0; i < 256; ++i) a2 += h[i] * fc3_w[(size_t)i * 40 + t];
            logits[(size_t)b * 40 + t] = a2;
        }
    }
}

// ---------------------------------------------------------------------------
extern "C" void kernel_launch(void* const* d_in, const int* in_sizes, int n_in,
                              void* d_out, int out_size, void* d_ws, size_t ws_size,
                              hipStream_t stream) {
    const float* x      = (const float*)d_in[0];
    // d_in[1] (x2) unused by the reference
    const float* L_reeb = (const float*)d_in[2];
    const float* W1     = (const float*)d_in[3];
    const float* b1     = (const float*)d_in[4];
    const float* W_reeb = (const float*)d_in[5];
    const float* b_reeb = (const float*)d_in[6];
    const float* W_fps  = (const float*)d_in[7];
    const float* b_fps  = (const float*)d_in[8];
    const float* fc1_w  = (const float*)d_in[9];
    const float* fc1_b  = (const float*)d_in[10];
    const float* fc3_w  = (const float*)d_in[11];
    const float* fc3_b  = (const float*)d_in[12];
    const int*   sccs   = (const int*)d_in[13];
    const int*   sccs_f = (const int*)d_in[14];

    float* outv = (float*)d_out;          // 32*40 logits
    float* regs = outv + 1280;            // 7 regs

    char* w = (char*)d_ws;
    size_t off = 0;
    auto alloc = [&](size_t bytes) { void* p = w + off; off = (off + bytes + 255) & ~(size_t)255; return p; };
    int*   knn   = (int*)  alloc((size_t)BN * NP * KNN * 4);
    float* xs1   = (float*)alloc((size_t)BN * NP * 7 * 4);
    float* outF  = (float*)alloc((size_t)BN * NP * 64 * 4);
    float* Z1    = (float*)alloc((size_t)BN * NP * 64 * 4);
    float* Vreeb = (float*)alloc((size_t)BN * NR * 64 * 4);
    float* outRb = (float*)alloc((size_t)BN * NR * 256 * 4);
    float* Z2    = (float*)alloc((size_t)BN * NR * 256 * 4);
    float* Vfps  = (float*)alloc((size_t)BN * NFPS * 64 * 4);
    float* Lfps  = (float*)alloc((size_t)BN * NFPS * NFPS * 4);
    float* outP  = (float*)alloc((size_t)BN * NFPS * 256 * 4);
    float* Z3    = (float*)alloc((size_t)BN * NFPS * 256 * 4);
    float* Cbuf  = (float*)alloc((size_t)BN * 4096 * 4);

    k_knn<<<dim3(BN, NP / 16), 256, 0, stream>>>(x, knn, xs1);
    k_out<<<dim3(BN, 17), 256, 0, stream>>>(x, xs1, knn, W1, b1, outF,
                                            fc1_w, fc1_b, fc3_w, fc3_b, regs, Cbuf);
    k_z1v<<<dim3(BN, 256 + 16 + NFPS), 256, 0, stream>>>(outF, knn, sccs, sccs_f,
                                                         Z1, Vreeb, Vfps);
    k_mid1<<<dim3(BN, 13), 256, 0, stream>>>(outF, Z1, Vfps, Cbuf, Lfps,
                                             L_reeb, Vreeb, W_reeb, b_reeb, outRb, Z2);
    k_mid2<<<dim3(BN, 21), 256, 0, stream>>>(Lfps, Vfps, W_fps, b_fps, outP, Z3,
                                             outRb, Z2, Cbuf, regs);
    k_fin<<<dim3(BN, 17), 256, 0, stream>>>(outP, Z3, outRb,
                                            fc1_w, fc1_b, fc3_w, fc3_b, regs, outv);
}

// Round 10
// 354.545 us; speedup vs baseline: 1.0367x; 1.0367x over previous
//
#include <hip/hip_runtime.h>
#include <math.h>

#define BN 32
#define NP 1024
#define KNN 30
#define NR 64
#define NFPS 55

// xls slot with a 4-float skew every 128 rows so the 8 segment-parallel
// b128 reads of a wave land on 32 distinct banks (seg base bank = 4*seg).
// (R9 lesson: 64-row segment pitch breaks this -- all segments land on
// bank 0 and conflicts cost ~14us. Keep 8 segments x 128.)
#define XSLOT(r) ((r) * 8 + ((r) >> 7) * 4)

// s = dinv*dinv with dinv = 1/sqrt(30) in f32, matching the reference's
// normalized laplacian (every kNN row-sum is exactly 30).
__device__ __forceinline__ float lap_s() {
    const float dv = 1.0f / sqrtf(30.0f);
    return dv * dv;
}

// Distance with ALL operations IEEE-pinned (contract off): guarantees the
// phase-A value and the phase-C recompute are bit-identical.
__device__ __forceinline__ float dist7(const float4& xiA, const float4& xiB,
                                       float sqi, const float4& ca, const float4& cb) {
#pragma clang fp contract(off)
    float dot = xiA.x * ca.x;
    dot = fmaf(xiA.y, ca.y, dot);
    dot = fmaf(xiA.z, ca.z, dot);
    dot = fmaf(xiA.w, ca.w, dot);
    dot = fmaf(xiB.x, cb.x, dot);
    dot = fmaf(xiB.y, cb.y, dot);
    dot = fmaf(xiB.z, cb.z, dot);
    float r = sqi + cb.w;
    r = r - 2.f * dot;
    return fmaxf(r, 0.f);
}

// ---------------------------------------------------------------------------
// k_knn: R4-proven body (VGPR 52, 0 bank conflicts, VALUBusy ~74%). 32 rows/
// block, 4 waves, 8 lanes/row each scanning a 128-candidate segment; med3
// value top-30 per lane; in-wave bitonic 8-way merge (shfl_xor); threshold
// rescan emits indices in ascending j; ns reduced by shfl butterfly.
// ---------------------------------------------------------------------------
__global__ __launch_bounds__(256, 4) void k_knn(const float* __restrict__ x,
                                                int* __restrict__ knn,
                                                float* __restrict__ xs1) {
    __shared__ float xls[8224];            // 32896 B: 7 feats + sq, skewed
    int b = blockIdx.x;
    int t = threadIdx.x;
    int ln = t & 63, wv = t >> 6;
    int seg = ln & 7;                      // candidate segment 0..7
    int rl  = ln >> 3;                     // row-in-wave 0..7

    const float* xb = x + (size_t)b * NP * 7;
#pragma unroll 4
    for (int k = 0; k < 32; ++k) {
        int q = k * 256 + t;
        int r = q >> 3, d = q & 7;
        float v = (d < 7) ? xb[r * 7 + d] : 0.f;
        float p2 = v * v;
        p2 += __shfl_xor(p2, 1);
        p2 += __shfl_xor(p2, 2);
        p2 += __shfl_xor(p2, 4);
        xls[XSLOT(r) + d] = (d < 7) ? v : p2;
    }
    __syncthreads();

    int grow = blockIdx.y * 32 + wv * 8 + rl;
    int gslot = XSLOT(grow);
    float4 xiA = *(const float4*)&xls[gslot];
    float4 xiB = *(const float4*)&xls[gslot + 4];
    float sqi = xiB.w;

    float bd[KNN];
#pragma unroll
    for (int q = 0; q < KNN; ++q) bd[q] = __builtin_inff();
    int jbase = seg * 128;
    int sbase = XSLOT(jbase);              // = jbase*8 + seg*4
    for (int jc = 0; jc < 128; jc += 4) {
        const float* p = &xls[sbase + jc * 8];
        float4 a0 = *(const float4*)(p +  0), b0 = *(const float4*)(p +  4);
        float4 a1 = *(const float4*)(p +  8), b1 = *(const float4*)(p + 12);
        float4 a2 = *(const float4*)(p + 16), b2 = *(const float4*)(p + 20);
        float4 a3 = *(const float4*)(p + 24), b3 = *(const float4*)(p + 28);
        float d0 = dist7(xiA, xiB, sqi, a0, b0);
        float d1 = dist7(xiA, xiB, sqi, a1, b1);
        float d2 = dist7(xiA, xiB, sqi, a2, b2);
        float d3 = dist7(xiA, xiB, sqi, a3, b3);
#pragma unroll
        for (int q = KNN - 1; q >= 1; --q) bd[q] = __builtin_amdgcn_fmed3f(bd[q - 1], d0, bd[q]);
        bd[0] = fminf(bd[0], d0);
#pragma unroll
        for (int q = KNN - 1; q >= 1; --q) bd[q] = __builtin_amdgcn_fmed3f(bd[q - 1], d1, bd[q]);
        bd[0] = fminf(bd[0], d1);
#pragma unroll
        for (int q = KNN - 1; q >= 1; --q) bd[q] = __builtin_amdgcn_fmed3f(bd[q - 1], d2, bd[q]);
        bd[0] = fminf(bd[0], d2);
#pragma unroll
        for (int q = KNN - 1; q >= 1; --q) bd[q] = __builtin_amdgcn_fmed3f(bd[q - 1], d3, bd[q]);
        bd[0] = fminf(bd[0], d3);
    }

    float m[32];
#pragma unroll
    for (int q = 0; q < KNN; ++q) m[q] = bd[q];
    m[30] = __builtin_inff(); m[31] = __builtin_inff();
#pragma unroll
    for (int lvl = 0; lvl < 3; ++lvl) {
        int mask = 1 << lvl;
#pragma unroll
        for (int q = 0; q < 16; ++q) {
            float u = __shfl_xor(m[31 - q], mask);
            float v = __shfl_xor(m[q], mask);
            float lo = fminf(m[q], u);
            float hi = fminf(m[31 - q], v);
            m[q] = lo; m[31 - q] = hi;
        }
#pragma unroll
        for (int d = 16; d >= 1; d >>= 1) {
#pragma unroll
            for (int i = 0; i < 32; ++i) {
                if ((i & d) == 0) {
                    float a = m[i], c = m[i | d];
                    m[i] = fminf(a, c);
                    m[i | d] = fmaxf(a, c);
                }
            }
        }
    }
    float T = m[29];
    int firstT = 0;
#pragma unroll
    for (int q = 0; q < KNN; ++q) firstT += (m[q] < T) ? 1 : 0;
    int need = KNN - firstT;               // global tie quota at T
    int cnt_lt = 0, cnt_eq = 0;
#pragma unroll
    for (int q = 0; q < KNN; ++q) {
        cnt_lt += (bd[q] < T) ? 1 : 0;
        cnt_eq += (bd[q] == T) ? 1 : 0;
    }
    int lanebase = ln & ~7;
    int pe = 0;
#pragma unroll
    for (int s2 = 0; s2 < 7; ++s2) {
        int v = __shfl(cnt_eq, lanebase + s2);
        pe += (s2 < seg) ? v : 0;
    }
    int e = need - pe;
    e = (e < 0) ? 0 : e;
    e = (e > cnt_eq) ? cnt_eq : e;
    int tk = cnt_lt + e;
    int pb = 0;
#pragma unroll
    for (int s2 = 0; s2 < 7; ++s2) {
        int v = __shfl(tk, lanebase + s2);
        pb += (s2 < seg) ? v : 0;
    }
    int base = pb;

    int* kout = knn + ((size_t)b * NP + grow) * KNN;
    float n0 = 0.f, n1 = 0.f, n2 = 0.f, n3 = 0.f, n4 = 0.f, n5 = 0.f, n6 = 0.f;
    int cs = 0, ct = 0;
    for (int jc = 0; jc < 128; jc += 4) {
        const float* p = &xls[sbase + jc * 8];
        float4 a0 = *(const float4*)(p +  0), b0 = *(const float4*)(p +  4);
        float4 a1 = *(const float4*)(p +  8), b1 = *(const float4*)(p + 12);
        float4 a2 = *(const float4*)(p + 16), b2 = *(const float4*)(p + 20);
        float4 a3 = *(const float4*)(p + 24), b3 = *(const float4*)(p + 28);
        float d0 = dist7(xiA, xiB, sqi, a0, b0);
        float d1 = dist7(xiA, xiB, sqi, a1, b1);
        float d2 = dist7(xiA, xiB, sqi, a2, b2);
        float d3 = dist7(xiA, xiB, sqi, a3, b3);
#pragma unroll
        for (int u = 0; u < 4; ++u) {
            float dist = (u == 0) ? d0 : (u == 1) ? d1 : (u == 2) ? d2 : d3;
            const float4& ca = (u == 0) ? a0 : (u == 1) ? a1 : (u == 2) ? a2 : a3;
            const float4& cb = (u == 0) ? b0 : (u == 1) ? b1 : (u == 2) ? b2 : b3;
            bool lt = dist < T;
            bool eq = (dist == T) && (ct < e);
            if ((lt || eq) && (cs + ct < tk)) {
                kout[base + cs + ct] = jbase + jc + u;
                cs += lt ? 1 : 0;
                ct += eq ? 1 : 0;
                n0 += ca.x; n1 += ca.y; n2 += ca.z; n3 += ca.w;
                n4 += cb.x; n5 += cb.y; n6 += cb.z;
            }
        }
    }
    for (int q = cs + ct; q < tk; ++q) kout[base + q] = grow;  // safety net
#pragma unroll
    for (int mask = 1; mask <= 4; mask <<= 1) {
        n0 += __shfl_xor(n0, mask);
        n1 += __shfl_xor(n1, mask);
        n2 += __shfl_xor(n2, mask);
        n3 += __shfl_xor(n3, mask);
        n4 += __shfl_xor(n4, mask);
        n5 += __shfl_xor(n5, mask);
        n6 += __shfl_xor(n6, mask);
    }
    if (seg < 7) {
        float nv = (seg == 0) ? n0 : (seg == 1) ? n1 : (seg == 2) ? n2 :
                   (seg == 3) ? n3 : (seg == 4) ? n4 : (seg == 5) ? n5 : n6;
        xs1[((size_t)b * NP + grow) * 7 + seg] = xls[gslot + seg] - lap_s() * nv;
    }
}

// ---------------------------------------------------------------------------
// k_out: xs2 = 2 L xs1 - x, then out = relu([x|xs1|xs2] @ W1 + b1), (B,N,64).
// Gather phase uses ALL 256 threads (4 per row, partials combined via LDS).
// y==16: zero Cbuf (all b); b==0 additionally does the one-off weight-reg init.
// ---------------------------------------------------------------------------
__global__ __launch_bounds__(256) void k_out(const float* __restrict__ x,
                                             const float* __restrict__ xs1,
                                             const int* __restrict__ knn,
                                             const float* __restrict__ W1,
                                             const float* __restrict__ b1,
                                             float* __restrict__ out,
                                             const float* __restrict__ fc1_w,
                                             const float* __restrict__ fc1_b,
                                             const float* __restrict__ fc3_w,
                                             const float* __restrict__ fc3_b,
                                             float* __restrict__ regs,
                                             float* __restrict__ Cbuf) {
    __shared__ float x1s[NP * 7];    // xs1 for ALL rows (neighbor gathers)
    __shared__ float x0s[64 * 7];    // x for this block's rows only
    __shared__ float fr[64 * 21];
    __shared__ float W1s[21 * 64];
    __shared__ float b1s[64];
    __shared__ float nsp[64 * 28];   // 4 partials x 7 dims per row
    int b = blockIdx.x, y = blockIdx.y;
    int t = threadIdx.x;
    if (y == 16) {                   // Cbuf zero (all b) + one-off init (b==0)
        float* cb = Cbuf + (size_t)b * 4096;
        for (int q = t; q < 4096; q += 256) cb[q] = 0.f;
        if (b != 0) return;
        float* r1 = x1s;             // overlay (x1s unused on this path)
        float* r2 = x1s + 256;
        float s1 = 0.f;
        for (int i = t; i < 512; i += 256) { float v = fc1_w[(size_t)i * 256]; s1 += v * v; }
        float v2 = fc3_w[(size_t)t * 40];
        r1[t] = s1; r2[t] = v2 * v2;
        __syncthreads();
        for (int st = 128; st > 0; st >>= 1) {
            if (t < st) { r1[t] += r1[t + st]; r2[t] += r2[t + st]; }
            __syncthreads();
        }
        if (t == 0) {
            regs[0] = 0.f; regs[1] = 0.f; regs[2] = 0.f;
            regs[3] = r1[0];
            regs[4] = fc1_b[0] * fc1_b[0];
            regs[5] = r2[0];
            regs[6] = fc3_b[0] * fc3_b[0];
        }
        return;
    }
    int rbase = y * 64;
    for (int q = t; q < NP * 7; q += 256) x1s[q] = xs1[(size_t)b * NP * 7 + q];
    for (int q = t; q < 64 * 7; q += 256) x0s[q] = x[(size_t)b * NP * 7 + (size_t)rbase * 7 + q];
    for (int q = t; q < 21 * 64; q += 256) W1s[q] = W1[q];
    if (t < 64) b1s[t] = b1[t];
    __syncthreads();
    {
        int row = t >> 2, tq = t & 3;
        int i = rbase + row;
        float ns[7] = {0.f, 0.f, 0.f, 0.f, 0.f, 0.f, 0.f};
        const int* kn = knn + ((size_t)b * NP + i) * KNN;
        for (int q = tq; q < KNN; q += 4) {
            int j = kn[q];
#pragma unroll
            for (int d = 0; d < 7; ++d) ns[d] += x1s[j * 7 + d];
        }
#pragma unroll
        for (int d = 0; d < 7; ++d) nsp[row * 28 + tq * 7 + d] = ns[d];
    }
    __syncthreads();
    if (t < 64) {
        int i = rbase + t;
        float f[21];
#pragma unroll
        for (int d = 0; d < 7; ++d) { f[d] = x0s[t * 7 + d]; f[7 + d] = x1s[i * 7 + d]; }
        const float s = lap_s();
#pragma unroll
        for (int d = 0; d < 7; ++d) {
            float ns = nsp[t * 28 + d] + nsp[t * 28 + 7 + d]
                     + nsp[t * 28 + 14 + d] + nsp[t * 28 + 21 + d];
            f[14 + d] = 2.f * (f[7 + d] - s * ns) - f[d];
        }
#pragma unroll
        for (int d = 0; d < 21; ++d) fr[t * 21 + d] = f[d];
    }
    __syncthreads();
    int o = t & 63, g = t >> 6;
    for (int m = 0; m < 16; ++m) {
        int r = g * 16 + m;
        float acc = b1s[o];
#pragma unroll
        for (int d = 0; d < 21; ++d) acc += fr[r * 21 + d] * W1s[d * 64 + o];
        out[((size_t)b * NP + rbase + r) * 64 + o] = fmaxf(acc, 0.f);
    }
}

// ---------------------------------------------------------------------------
// k_z1v: fused Z1 = L@out gather + segment-max pools. Grid (B, 256+16+55):
//   y<256  -> Z1 rows y*4..y*4+3
//   y<272  -> V_reeb rows (y-256)*4.. (16-segment max)
//   else   -> V_fps row p=y-272: 1024-bit dedupe bitmap
// ---------------------------------------------------------------------------
__global__ __launch_bounds__(256) void k_z1v(const float* __restrict__ out,
                                             const int* __restrict__ knn,
                                             const int* __restrict__ sccs,
                                             const int* __restrict__ sccs_fps,
                                             float* __restrict__ Z1,
                                             float* __restrict__ Vr,
                                             float* __restrict__ Vf) {
    __shared__ unsigned bmw[32];
    __shared__ float red[256];
    int b = blockIdx.x, y = blockIdx.y;
    int t = threadIdx.x;
    const float* ob = out + (size_t)b * NP * 64;
    if (y < 256) {
        int i = y * 4 + (t >> 6);
        int f = t & 63;
        const int* kn = knn + ((size_t)b * NP + i) * KNN;
        float sum = 0.f;
        for (int q = 0; q < KNN; ++q) sum += ob[(size_t)kn[q] * 64 + f];
        Z1[((size_t)b * NP + i) * 64 + f] = ob[(size_t)i * 64 + f] - lap_s() * sum;
    } else if (y < 272) {
        int r = (y - 256) * 4 + (t >> 6);
        int f = t & 63;
        const int* sc = sccs + ((size_t)b * NR + r) * 16;
        float m = -__builtin_inff();
        for (int q = 0; q < 16; ++q) m = fmaxf(m, ob[(size_t)sc[q] * 64 + f]);
        Vr[((size_t)b * NR + r) * 64 + f] = m;
    } else {
        int p = y - 272;
        const int* sp = sccs_fps + ((size_t)b * NFPS + p) * 1024;
        if (t < 32) bmw[t] = 0u;
        __syncthreads();
        for (int q = t; q < 1024; q += 256) {
            int r = sp[q];
            atomicOr(&bmw[r >> 5], 1u << (r & 31));
        }
        __syncthreads();
        int f = t & 63, sc = t >> 6;
        float m = -__builtin_inff();
        for (int w0 = sc * 8; w0 < sc * 8 + 8; ++w0) {
            unsigned w = bmw[w0];
            while (w) {
                int bit = __ffs(w) - 1;
                w &= w - 1;
                m = fmaxf(m, ob[(size_t)(w0 * 32 + bit) * 64 + f]);
            }
        }
        red[t] = m; __syncthreads();
        if (sc == 0) {
            m = fmaxf(fmaxf(red[f], red[64 + f]), fmaxf(red[128 + f], red[192 + f]));
            Vf[((size_t)b * NFPS + p) * 64 + f] = m;
        }
    }
}

// ---------------------------------------------------------------------------
// t1_part: partial C += out[chunk]^T @ Z1[chunk] (64x64, K-chunk of 128 rows),
// 4x4 register tile, atomicAdd into Cbuf[b].
// ---------------------------------------------------------------------------
__device__ __forceinline__ void t1_part(const float* __restrict__ out,
                                        const float* __restrict__ Z1,
                                        float* __restrict__ Cbuf,
                                        float* buf, int y) {
    int b = blockIdx.x, t = threadIdx.x;
    float* os = buf;          // 128*64
    float* zs = buf + 8192;   // 128*64
    const float* ob = out + ((size_t)b * NP + (size_t)y * 128) * 64;
    const float* zb = Z1 + ((size_t)b * NP + (size_t)y * 128) * 64;
    for (int q = t; q < 128 * 64; q += 256) { os[q] = ob[q]; zs[q] = zb[q]; }
    __syncthreads();
    int f0 = (t & 15) * 4, g0 = (t >> 4) * 4;
    float4 ac0 = make_float4(0.f, 0.f, 0.f, 0.f);
    float4 ac1 = ac0, ac2 = ac0, ac3 = ac0;
#pragma unroll 4
    for (int n = 0; n < 128; ++n) {
        float4 ov = *(const float4*)&os[n * 64 + f0];
        float4 zv = *(const float4*)&zs[n * 64 + g0];
        ac0.x += ov.x * zv.x; ac0.y += ov.x * zv.y; ac0.z += ov.x * zv.z; ac0.w += ov.x * zv.w;
        ac1.x += ov.y * zv.x; ac1.y += ov.y * zv.y; ac1.z += ov.y * zv.z; ac1.w += ov.y * zv.w;
        ac2.x += ov.z * zv.x; ac2.y += ov.z * zv.y; ac2.z += ov.z * zv.z; ac2.w += ov.z * zv.w;
        ac3.x += ov.w * zv.x; ac3.y += ov.w * zv.y; ac3.z += ov.w * zv.z; ac3.w += ov.w * zv.w;
    }
    float* cb = Cbuf + (size_t)b * 4096;
    atomicAdd(&cb[(f0 + 0) * 64 + g0 + 0], ac0.x);
    atomicAdd(&cb[(f0 + 0) * 64 + g0 + 1], ac0.y);
    atomicAdd(&cb[(f0 + 0) * 64 + g0 + 2], ac0.z);
    atomicAdd(&cb[(f0 + 0) * 64 + g0 + 3], ac0.w);
    atomicAdd(&cb[(f0 + 1) * 64 + g0 + 0], ac1.x);
    atomicAdd(&cb[(f0 + 1) * 64 + g0 + 1], ac1.y);
    atomicAdd(&cb[(f0 + 1) * 64 + g0 + 2], ac1.z);
    atomicAdd(&cb[(f0 + 1) * 64 + g0 + 3], ac1.w);
    atomicAdd(&cb[(f0 + 2) * 64 + g0 + 0], ac2.x);
    atomicAdd(&cb[(f0 + 2) * 64 + g0 + 1], ac2.y);
    atomicAdd(&cb[(f0 + 2) * 64 + g0 + 2], ac2.z);
    atomicAdd(&cb[(f0 + 2) * 64 + g0 + 3], ac2.w);
    atomicAdd(&cb[(f0 + 3) * 64 + g0 + 0], ac3.x);
    atomicAdd(&cb[(f0 + 3) * 64 + g0 + 1], ac3.y);
    atomicAdd(&cb[(f0 + 3) * 64 + g0 + 2], ac3.z);
    atomicAdd(&cb[(f0 + 3) * 64 + g0 + 3], ac3.w);
}

// ---------------------------------------------------------------------------
// lfps_impl: L_fps build from V_fps (R10-proven body)
// ---------------------------------------------------------------------------
__device__ __forceinline__ void lfps_impl(const float* __restrict__ Vfps,
                                          float* __restrict__ Lf, float* buf) {
    int b = blockIdx.x;
    int t = threadIdx.x;
    float* Vs = buf;                    // 55*64 = 3520
    float* sq = buf + 3520;             // 55 (pad to 3584)
    float* dist = buf + 3584;           // 55*55 = 3025
    float* dinv = buf + 6609;           // 55
    for (int q = t; q < NFPS * 64; q += 256) Vs[q] = Vfps[(size_t)b * NFPS * 64 + q];
    __syncthreads();
    if (t < NFPS) {
        float s = 0.f;
        for (int f = 0; f < 64; ++f) { float v = Vs[t * 64 + f]; s += v * v; }
        sq[t] = s;
    }
    __syncthreads();
    for (int q = t; q < NFPS * NFPS; q += 256) {
        int i = q / NFPS, j = q % NFPS;
        float dot = 0.f;
        for (int f = 0; f < 64; ++f) dot += Vs[i * 64 + f] * Vs[j * 64 + f];
        dist[q] = fmaxf(sq[i] + sq[j] - 2.f * dot, 0.f);
    }
    __syncthreads();
    if (t < NFPS) {
        float s = 0.f;
        for (int j = 0; j < NFPS; ++j) s += dist[t * NFPS + j];
        dinv[t] = (s > 0.f) ? 1.0f / sqrtf(fmaxf(s, 1e-12f)) : 0.f;
    }
    __syncthreads();
    for (int q = t; q < NFPS * NFPS; q += 256) {
        int i = q / NFPS, j = q % NFPS;
        Lf[(size_t)b * NFPS * NFPS + q] = ((i == j) ? 1.f : 0.f) - dist[q] * dinv[i] * dinv[j];
    }
}

// ---------------------------------------------------------------------------
// cheb_impl<N>: K=6 Chebyshev conv + relu + Z = L @ out, one batch, one
// 64-wide output-column slice. Register-tiled 4x4 per thread, float4 LDS
// reads both operands. Pad rows/cols zeroed so N=55 needs no read guards.
// m-loops pinned to unroll 2 (toolchain-drift defense; see R17/R5 notes:
// 112KB smem and 8-wide lane tiles are both proven regressions).
// ---------------------------------------------------------------------------
template<int N>
__device__ __forceinline__ void cheb_impl(const float* __restrict__ L,
                                          const float* __restrict__ V,
                                          const float* __restrict__ W,
                                          const float* __restrict__ bias,
                                          float* __restrict__ out,
                                          float* __restrict__ Z,
                                          float* Ls, float* bA, float* bB, float* Ws,
                                          int b, int sl) {
    constexpr int NPAD = (N + 3) & ~3;   // 64 or 56
    int t = threadIdx.x;
    int c0 = (t & 15) * 4;               // 0..60
    int r0 = (t >> 4) * 4;               // 0..60

    for (int q = t; q < 64 * 64; q += 256) { Ls[q] = 0.f; bA[q] = 0.f; bB[q] = 0.f; }
    __syncthreads();
    for (int q = t; q < N * N; q += 256) {
        int r = q / N, m = q % N;
        Ls[r * 64 + m] = L[(size_t)b * N * N + q];
    }
    for (int q = t; q < N * 64; q += 256) bA[q] = V[(size_t)b * N * 64 + q];
    {
        const float* Wk = W + sl * 64;
        for (int q = t; q < 64 * 64; q += 256) Ws[q] = Wk[(q >> 6) * 256 + (q & 63)];
    }
    float4 a4[4];
    {
        float4 bv = *(const float4*)&bias[sl * 64 + c0];
#pragma unroll
        for (int i = 0; i < 4; ++i) a4[i] = bv;
    }
    __syncthreads();

    auto accum = [&](const float* xb) {
#pragma unroll 2
        for (int m = 0; m < 64; m += 4) {
            float4 xv[4], wv[4];
#pragma unroll
            for (int i = 0; i < 4; ++i) xv[i] = *(const float4*)&xb[(r0 + i) * 64 + m];
#pragma unroll
            for (int mm = 0; mm < 4; ++mm) wv[mm] = *(const float4*)&Ws[(m + mm) * 64 + c0];
#pragma unroll
            for (int i = 0; i < 4; ++i) {
                float xi0 = xv[i].x, xi1 = xv[i].y, xi2 = xv[i].z, xi3 = xv[i].w;
                a4[i].x += xi0 * wv[0].x; a4[i].y += xi0 * wv[0].y; a4[i].z += xi0 * wv[0].z; a4[i].w += xi0 * wv[0].w;
                a4[i].x += xi1 * wv[1].x; a4[i].y += xi1 * wv[1].y; a4[i].z += xi1 * wv[1].z; a4[i].w += xi1 * wv[1].w;
                a4[i].x += xi2 * wv[2].x; a4[i].y += xi2 * wv[2].y; a4[i].z += xi2 * wv[2].z; a4[i].w += xi2 * wv[2].w;
                a4[i].x += xi3 * wv[3].x; a4[i].y += xi3 * wv[3].y; a4[i].z += xi3 * wv[3].z; a4[i].w += xi3 * wv[3].w;
            }
        }
    };
    auto chebmm = [&](const float* src, float* dst, bool first) {
        float4 acc[4];
#pragma unroll
        for (int i = 0; i < 4; ++i) acc[i] = make_float4(0.f, 0.f, 0.f, 0.f);
#pragma unroll 2
        for (int m = 0; m < NPAD; m += 4) {
            float4 sv[4], lv[4];
#pragma unroll
            for (int mm = 0; mm < 4; ++mm) sv[mm] = *(const float4*)&src[(m + mm) * 64 + c0];
#pragma unroll
            for (int i = 0; i < 4; ++i) lv[i] = *(const float4*)&Ls[(r0 + i) * 64 + m];
#pragma unroll
            for (int i = 0; i < 4; ++i) {
                float l0 = lv[i].x, l1 = lv[i].y, l2 = lv[i].z, l3 = lv[i].w;
                acc[i].x += l0 * sv[0].x; acc[i].y += l0 * sv[0].y; acc[i].z += l0 * sv[0].z; acc[i].w += l0 * sv[0].w;
                acc[i].x += l1 * sv[1].x; acc[i].y += l1 * sv[1].y; acc[i].z += l1 * sv[1].z; acc[i].w += l1 * sv[1].w;
                acc[i].x += l2 * sv[2].x; acc[i].y += l2 * sv[2].y; acc[i].z += l2 * sv[2].z; acc[i].w += l2 * sv[2].w;
                acc[i].x += l3 * sv[3].x; acc[i].y += l3 * sv[3].y; acc[i].z += l3 * sv[3].z; acc[i].w += l3 * sv[3].w;
            }
        }
#pragma unroll
        for (int i = 0; i < 4; ++i) {
            if (r0 + i < N) {
                float4* d = (float4*)&dst[(r0 + i) * 64 + c0];
                if (first) *d = acc[i];
                else {
                    float4 od = *d;
                    *d = make_float4(2.f * acc[i].x - od.x, 2.f * acc[i].y - od.y,
                                     2.f * acc[i].z - od.z, 2.f * acc[i].w - od.w);
                }
            }
        }
    };
    auto loadW = [&](int k) {
        const float* Wk = W + (size_t)k * 64 * 256 + sl * 64;
        for (int q = t; q < 64 * 64; q += 256) Ws[q] = Wk[(q >> 6) * 256 + (q & 63)];
    };

    accum(bA);                 __syncthreads();
    chebmm(bA, bB, true);      loadW(1);  __syncthreads();
    accum(bB);                 __syncthreads();
    chebmm(bB, bA, false);     loadW(2);  __syncthreads();
    accum(bA);                 __syncthreads();
    chebmm(bA, bB, false);     loadW(3);  __syncthreads();
    accum(bB);                 __syncthreads();
    chebmm(bB, bA, false);     loadW(4);  __syncthreads();
    accum(bA);                 __syncthreads();
    chebmm(bA, bB, false);     loadW(5);  __syncthreads();
    accum(bB);                 __syncthreads();

    float* ob = out + (size_t)b * N * 256 + sl * 64;
#pragma unroll
    for (int i = 0; i < 4; ++i) {
        if (r0 + i < N) {
            float4 v = make_float4(fmaxf(a4[i].x, 0.f), fmaxf(a4[i].y, 0.f),
                                   fmaxf(a4[i].z, 0.f), fmaxf(a4[i].w, 0.f));
            *(float4*)&bA[(r0 + i) * 64 + c0] = v;
            *(float4*)&ob[(size_t)(r0 + i) * 256 + c0] = v;
        }
    }
    __syncthreads();
    {
        float4 acc[4];
#pragma unroll
        for (int i = 0; i < 4; ++i) acc[i] = make_float4(0.f, 0.f, 0.f, 0.f);
#pragma unroll 2
        for (int m = 0; m < NPAD; m += 4) {
            float4 sv[4], lv[4];
#pragma unroll
            for (int mm = 0; mm < 4; ++mm) sv[mm] = *(const float4*)&bA[(m + mm) * 64 + c0];
#pragma unroll
            for (int i = 0; i < 4; ++i) lv[i] = *(const float4*)&Ls[(r0 + i) * 64 + m];
#pragma unroll
            for (int i = 0; i < 4; ++i) {
                float l0 = lv[i].x, l1 = lv[i].y, l2 = lv[i].z, l3 = lv[i].w;
                acc[i].x += l0 * sv[0].x; acc[i].y += l0 * sv[0].y; acc[i].z += l0 * sv[0].z; acc[i].w += l0 * sv[0].w;
                acc[i].x += l1 * sv[1].x; acc[i].y += l1 * sv[1].y; acc[i].z += l1 * sv[1].z; acc[i].w += l1 * sv[1].w;
                acc[i].x += l2 * sv[2].x; acc[i].y += l2 * sv[2].y; acc[i].z += l2 * sv[2].z; acc[i].w += l2 * sv[2].w;
                acc[i].x += l3 * sv[3].x; acc[i].y += l3 * sv[3].y; acc[i].z += l3 * sv[3].z; acc[i].w += l3 * sv[3].w;
            }
        }
        float* zb = Z + (size_t)b * N * 256 + sl * 64;
#pragma unroll
        for (int i = 0; i < 4; ++i)
            if (r0 + i < N) *(float4*)&zb[(size_t)(r0 + i) * 256 + c0] = acc[i];
    }
}

// ---------------------------------------------------------------------------
// treg_impl<N>: reg += sum((out^T Z)^2) for one (f-tile, g-half) pair.
// (R7 lesson: the 2x-cheaper Gram form LOST 10us -- 32 blocks/network vs
// 512+: at this scale block count beats op count. Keep treg.)
// ---------------------------------------------------------------------------
template<int N>
__device__ __forceinline__ void treg_impl(const float* __restrict__ out,
                                          const float* __restrict__ Z,
                                          float* __restrict__ reg,
                                          float* zs, float* os, float* red, int y) {
    int b = blockIdx.x;
    int f0 = (y >> 1) * 32;
    int g0 = (y & 1) * 128;
    int t = threadIdx.x;
    for (int q = t; q < N * 128; q += 256) {
        int r = q >> 7, gl = q & 127;
        zs[q] = Z[(size_t)b * N * 256 + r * 256 + g0 + gl];
    }
    for (int q = t; q < N * 32; q += 256) {
        int r = q >> 5, f = q & 31;
        os[q] = out[(size_t)b * N * 256 + r * 256 + f0 + f];
    }
    __syncthreads();
    int fl = t >> 3;           // 0..31
    int gb = (t & 7) * 16;     // 0..112
    float accv[16];
#pragma unroll
    for (int q = 0; q < 16; ++q) accv[q] = 0.f;
    for (int n = 0; n < N; ++n) {
        float a = os[n * 32 + fl];
        const float* zr = zs + n * 128 + gb;
#pragma unroll
        for (int q = 0; q < 16; ++q) accv[q] += a * zr[q];
    }
    float loc = 0.f;
#pragma unroll
    for (int q = 0; q < 16; ++q) loc += accv[q] * accv[q];
    red[t] = loc; __syncthreads();
    for (int st = 128; st > 0; st >>= 1) { if (t < st) red[t] += red[t + st]; __syncthreads(); }
    if (t == 0) atomicAdd(reg, red[0]);
}

// ---------------------------------------------------------------------------
// k_mid1: fused independent stage (R6-proven arrangement). Grid (B, 13):
//   y<8  -> t1 partial C chunk y (rows y*128..)
//   y==8 -> L_fps build (read by k_mid2 next launch)
//   y>8  -> cheb_reeb output slice y-9
// ---------------------------------------------------------------------------
__global__ __launch_bounds__(256) void k_mid1(
        const float* __restrict__ out, const float* __restrict__ Z1,
        const float* __restrict__ Vfps, float* __restrict__ Cbuf,
        float* __restrict__ Lf,
        const float* __restrict__ Lr, const float* __restrict__ Vr,
        const float* __restrict__ Wr, const float* __restrict__ br,
        float* __restrict__ outR, float* __restrict__ Zr) {
    __shared__ float smem[16384];    // 64 KB union
    int y = blockIdx.y;
    if (y < 8)       t1_part(out, Z1, Cbuf, smem, y);
    else if (y == 8) lfps_impl(Vfps, Lf, smem);
    else cheb_impl<NR>(Lr, Vr, Wr, br, outR, Zr,
                       smem, smem + 4096, smem + 8192, smem + 12288,
                       blockIdx.x, y - 9);
}

// ---------------------------------------------------------------------------
// k_mid2: Grid (B, 21): y<4 -> cheb_fps slice y (needs L_fps from k_mid1);
//   y in 4..19 -> treg_reeb tile y-4 (needs outR/Zr from k_mid1);
//   y==20 -> reg1 = sum(Cbuf^2) (needs all t1 partials from k_mid1).
// ---------------------------------------------------------------------------
__global__ __launch_bounds__(256) void k_mid2(
        const float* __restrict__ Lf, const float* __restrict__ Vf,
        const float* __restrict__ Wf, const float* __restrict__ bf,
        float* __restrict__ outP, float* __restrict__ Zf,
        const float* __restrict__ outR, const float* __restrict__ Zr,
        const float* __restrict__ Cbuf, float* __restrict__ regs) {
    __shared__ float smem[16384];    // 64 KB union
    int y = blockIdx.y;
    if (y < 4) cheb_impl<NFPS>(Lf, Vf, Wf, bf, outP, Zf,
                               smem, smem + 4096, smem + 8192, smem + 12288,
                               blockIdx.x, y);
    else if (y < 20) treg_impl<NR>(outR, Zr, regs + 1, smem, smem + 8192, smem + 10240, y - 4);
    else {
        int b = blockIdx.x, t = threadIdx.x;
        float* red = smem;
        float loc = 0.f;
        for (int q = t; q < 4096; q += 256) { float v = Cbuf[(size_t)b * 4096 + q]; loc += v * v; }
        red[t] = loc; __syncthreads();
        for (int st = 128; st > 0; st >>= 1) { if (t < st) red[t] += red[t + st]; __syncthreads(); }
        if (t == 0) atomicAdd(&regs[0], red[0]);
    }
}

// ---------------------------------------------------------------------------
// k_fin: Grid (B, 17): y<16 -> treg_fps tile y (needs outP/Zf from k_mid2);
//   y==16 -> per-batch maxpool + MLP -> logits.
// ---------------------------------------------------------------------------
__global__ __launch_bounds__(256) void k_fin(
        const float* __restrict__ outP, const float* __restrict__ Zf,
        const float* __restrict__ outR,
        const float* __restrict__ fc1_w, const float* __restrict__ fc1_b,
        const float* __restrict__ fc3_w, const float* __restrict__ fc3_b,
        float* __restrict__ regs, float* __restrict__ logits) {
    __shared__ float smem[10496];    // 41 KB
    int y = blockIdx.y;
    if (y < 16) treg_impl<NFPS>(outP, Zf, regs + 2, smem, smem + 8192, smem + 10240, y);
    else {
        int b = blockIdx.x, t = threadIdx.x;
        float* feat = smem;            // 512 floats
        float* h = smem + 1024;        // 256 floats
        float m = -__builtin_inff();
        for (int r = 0; r < NR; ++r) m = fmaxf(m, outR[((size_t)b * NR + r) * 256 + t]);
        feat[t] = m;
        m = -__builtin_inff();
        for (int p = 0; p < NFPS; ++p) m = fmaxf(m, outP[((size_t)b * NFPS + p) * 256 + t]);
        feat[256 + t] = m;
        __syncthreads();
        float a = fc1_b[t];
        for (int i = 0; i < 512; ++i) a += feat[i] * fc1_w[(size_t)i * 256 + t];
        h[t] = fmaxf(a, 0.f);
        __syncthreads();
        if (t < 40) {
            float a2 = fc3_b[t];
            for (int i = 0; i < 256; ++i) a2 += h[i] * fc3_w[(size_t)i * 40 + t];
            logits[(size_t)b * 40 + t] = a2;
        }
    }
}

// ---------------------------------------------------------------------------
extern "C" void kernel_launch(void* const* d_in, const int* in_sizes, int n_in,
                              void* d_out, int out_size, void* d_ws, size_t ws_size,
                              hipStream_t stream) {
    const float* x      = (const float*)d_in[0];
    // d_in[1] (x2) unused by the reference
    const float* L_reeb = (const float*)d_in[2];
    const float* W1     = (const float*)d_in[3];
    const float* b1     = (const float*)d_in[4];
    const float* W_reeb = (const float*)d_in[5];
    const float* b_reeb = (const float*)d_in[6];
    const float* W_fps  = (const float*)d_in[7];
    const float* b_fps  = (const float*)d_in[8];
    const float* fc1_w  = (const float*)d_in[9];
    const float* fc1_b  = (const float*)d_in[10];
    const float* fc3_w  = (const float*)d_in[11];
    const float* fc3_b  = (const float*)d_in[12];
    const int*   sccs   = (const int*)d_in[13];
    const int*   sccs_f = (const int*)d_in[14];

    float* outv = (float*)d_out;          // 32*40 logits
    float* regs = outv + 1280;            // 7 regs

    char* w = (char*)d_ws;
    size_t off = 0;
    auto alloc = [&](size_t bytes) { void* p = w + off; off = (off + bytes + 255) & ~(size_t)255; return p; };
    int*   knn   = (int*)  alloc((size_t)BN * NP * KNN * 4);
    float* xs1   = (float*)alloc((size_t)BN * NP * 7 * 4);
    float* outF  = (float*)alloc((size_t)BN * NP * 64 * 4);
    float* Z1    = (float*)alloc((size_t)BN * NP * 64 * 4);
    float* Vreeb = (float*)alloc((size_t)BN * NR * 64 * 4);
    float* outRb = (float*)alloc((size_t)BN * NR * 256 * 4);
    float* Z2    = (float*)alloc((size_t)BN * NR * 256 * 4);
    float* Vfps  = (float*)alloc((size_t)BN * NFPS * 64 * 4);
    float* Lfps  = (float*)alloc((size_t)BN * NFPS * NFPS * 4);
    float* outP  = (float*)alloc((size_t)BN * NFPS * 256 * 4);
    float* Z3    = (float*)alloc((size_t)BN * NFPS * 256 * 4);
    float* Cbuf  = (float*)alloc((size_t)BN * 4096 * 4);

    k_knn<<<dim3(BN, NP / 32), 256, 0, stream>>>(x, knn, xs1);
    k_out<<<dim3(BN, 17), 256, 0, stream>>>(x, xs1, knn, W1, b1, outF,
                                            fc1_w, fc1_b, fc3_w, fc3_b, regs, Cbuf);
    k_z1v<<<dim3(BN, 256 + 16 + NFPS), 256, 0, stream>>>(outF, knn, sccs, sccs_f,
                                                         Z1, Vreeb, Vfps);
    k_mid1<<<dim3(BN, 13), 256, 0, stream>>>(outF, Z1, Vfps, Cbuf, Lfps,
                                             L_reeb, Vreeb, W_reeb, b_reeb, outRb, Z2);
    k_mid2<<<dim3(BN, 21), 256, 0, stream>>>(Lfps, Vfps, W_fps, b_fps, outP, Z3,
                                             outRb, Z2, Cbuf, regs);
    k_fin<<<dim3(BN, 17), 256, 0, stream>>>(outP, Z3, outRb,
                                            fc1_w, fc1_b, fc3_w, fc3_b, regs, outv);
}